// Round 5
// baseline (589.910 us; speedup 1.0000x reference)
//
#include <hip/hip_runtime.h>
#include <hip/hip_bf16.h>
#include <cstdint>
#include <cstddef>

// HierarchicalAttention on MI355X (gfx950).
// R8 = R7 with the occupancy request fixed. R7's __launch_bounds__(256,6)
// capped the allocator at ~84 VGPR (pool 512/lane/SIMD, 6 waves/SIMD) vs an
// estimated ~130 live -> massive scratch spill in the window loop; likely the
// bench-failure cause. Now (256,4): 128-VGPR cap, 4 waves/SIMD (16 waves/CU).
// Structure unchanged from R7: K loaded DIRECTLY into MFMA B-fragment
// registers from global (no K LDS, no DMA); V cooperatively transposed
// through Vt[dbuf] (only cross-wave LDS) so the per-window barrier needs only
// lgkmcnt(0); all next-window loads (V,K,Q) issue one window ahead and are
// never drained by the barrier. LDS 24KB. WPB=4, grid 2048.
// gemm256 (212us qkv, FETCH/WRITE at ideal, 0 conflicts) and casts unchanged.
//
// Workspace layout (total 343,932,928 B):
//   [0)            x_bf16     [32768,1024]  67,108,864 B
//   [67108864)     wqkv_bf16  [3072,1024]    6,291,456 B
//   [73400320)     wproj_bf16 [1024,1024]    2,097,152 B
//   [75497472)     qkv_bf16   [32768,3072] 201,326,592 B
//   [276824064)    attn_bf16  [32768,1024]  67,108,864 B

typedef __attribute__((ext_vector_type(8))) short short8;
typedef __attribute__((ext_vector_type(4))) float float4v;

static __device__ __forceinline__ void async16(void* lds_p, const void* g) {
  __builtin_amdgcn_global_load_lds((const __attribute__((address_space(1))) void*)g,
                                   (__attribute__((address_space(3))) void*)lds_p,
                                   16, 0, 0);
}

static __device__ __forceinline__ unsigned short f2bf_bits(float x) {
  unsigned int u = __float_as_uint(x);
  unsigned int r = (u + 0x7fffu + ((u >> 16) & 1u)) >> 16;  // RNE
  return (unsigned short)r;
}

#define S_BARRIER() asm volatile("s_barrier" ::: "memory")
#define WAIT_VM(n)  asm volatile("s_waitcnt vmcnt(" #n ")" ::: "memory")
#define WAIT_LGKM0() asm volatile("s_waitcnt lgkmcnt(0)" ::: "memory")

// ---------------- cast fp32 -> bf16 (vectorized) ---------------------------
__global__ __launch_bounds__(256) void cast_f32_to_bf16(
    const float* __restrict__ in, unsigned short* __restrict__ out, int n4) {
  int i = blockIdx.x * 256 + threadIdx.x;
  if (i >= n4) return;
  float4 v = ((const float4*)in)[i];
  ushort4 o;
  o.x = f2bf_bits(v.x); o.y = f2bf_bits(v.y);
  o.z = f2bf_bits(v.z); o.w = f2bf_bits(v.w);
  ((ushort4*)out)[i] = o;
}

// ---------------- GEMM: C[M,N] = A[M,K] * B[N,K]^T + bias ------------------
// 256x256 tile, BK=64, 8 waves (2Mx4N), 8-phase counted-vmcnt schedule
// (T1..T5) + bf16 LDS-repack epilogue. Unchanged from R4.
template<bool OUT_BF16>
__global__ __launch_bounds__(512, 2) void gemm256(
    const unsigned short* __restrict__ A,   // [M,K] bf16 bits
    const unsigned short* __restrict__ B,   // [N,K] bf16 bits
    const float* __restrict__ bias,         // [N]
    void* __restrict__ Cout,                // [M,N] bf16 or fp32
    int M, int N, int K, int ntiles)
{
  extern __shared__ unsigned short lds[];

  const int t    = threadIdx.x;             // 0..511
  const int wave = t >> 6;
  const int lane = t & 63;
  const int lr   = lane & 15;
  const int lq   = lane >> 4;
  const int wm   = wave >> 2;               // 0..1
  const int wn   = wave & 3;                // 0..3

  const int nwg  = gridDim.x;
  const int q8   = nwg >> 3;
  const int wg   = ((int)blockIdx.x & 7) * q8 + ((int)blockIdx.x >> 3);
  const int GM   = 8;
  const int group = wg / (GM * ntiles);
  const int inG   = wg % (GM * ntiles);
  const int bm    = group * GM + (inG % GM);
  const int bn    = inG / GM;

  const int srow = t >> 3;                            // 0..63 within chunk
  const int sswz = ((t & 7) ^ (srow & 7)) << 3;       // swizzled col (elems)
  const unsigned short* Abase = A + (size_t)(bm * 256 + srow) * K + sswz;
  const unsigned short* Bbase = B + (size_t)(bn * 256 + srow) * K + sswz;
  const int ldsw = wave * 512;

  auto stageA = [&](int kt, int c) {
    async16(lds + (kt & 1) * 16384 + c * 4096 + ldsw,
            Abase + (size_t)(c * 64) * K + kt * 64);
  };
  auto stageB = [&](int kt, int c) {
    async16(lds + 32768 + (kt & 1) * 16384 + c * 4096 + ldsw,
            Bbase + (size_t)(c * 64) * K + kt * 64);
  };

  const int g0 = ((0 + lq) ^ (lr & 7)) << 3;
  const int g1 = ((4 + lq) ^ (lr & 7)) << 3;
  const int arow0 = (wm * 128 + lr) * 64;
  const int brow0 = (wn * 64 + lr) * 64;

  float4v acc[8][4];
  #pragma unroll
  for (int i = 0; i < 8; ++i)
    #pragma unroll
    for (int j = 0; j < 4; ++j) acc[i][j] = (float4v){0.f, 0.f, 0.f, 0.f};

  const int NT = K >> 6;

  #pragma unroll
  for (int c = 0; c < 4; ++c) stageB(0, c);
  #pragma unroll
  for (int c = 0; c < 4; ++c) stageA(0, c);
  #pragma unroll
  for (int c = 0; c < 4; ++c) stageB(1, c);
  WAIT_VM(4);
  S_BARRIER();

  short8 af[4][2], bf[2][2], bf2[2][2];

  for (int kt = 0; kt < NT; ++kt) {
    const int bc = kt & 1;
    int kt1 = kt + 1; if (kt1 == NT) kt1 = 0;
    int kt2 = kt + 2; if (kt2 >= NT) kt2 -= NT;
    const unsigned short* Al = lds + bc * 16384;
    const unsigned short* Bl = lds + 32768 + bc * 16384;

    // ---- phase 0
    #pragma unroll
    for (int mf = 0; mf < 4; ++mf) {
      af[mf][0] = *(const short8*)(Al + arow0 + mf * 1024 + g0);
      af[mf][1] = *(const short8*)(Al + arow0 + mf * 1024 + g1);
    }
    #pragma unroll
    for (int nf = 0; nf < 2; ++nf) {
      bf[nf][0] = *(const short8*)(Bl + brow0 + nf * 1024 + g0);
      bf[nf][1] = *(const short8*)(Bl + brow0 + nf * 1024 + g1);
    }
    stageA(kt1, 0); stageA(kt1, 2);
    S_BARRIER();
    __builtin_amdgcn_s_setprio(1);
    #pragma unroll
    for (int mf = 0; mf < 4; ++mf)
      #pragma unroll
      for (int nf = 0; nf < 2; ++nf) {
        acc[mf][nf] = __builtin_amdgcn_mfma_f32_16x16x32_bf16(af[mf][0], bf[nf][0], acc[mf][nf], 0, 0, 0);
        acc[mf][nf] = __builtin_amdgcn_mfma_f32_16x16x32_bf16(af[mf][1], bf[nf][1], acc[mf][nf], 0, 0, 0);
      }
    __builtin_amdgcn_s_setprio(0);
    S_BARRIER();

    // ---- phase 1
    #pragma unroll
    for (int nf = 0; nf < 2; ++nf) {
      bf2[nf][0] = *(const short8*)(Bl + brow0 + (2 + nf) * 1024 + g0);
      bf2[nf][1] = *(const short8*)(Bl + brow0 + (2 + nf) * 1024 + g1);
    }
    stageA(kt1, 1); stageA(kt1, 3);
    S_BARRIER();
    __builtin_amdgcn_s_setprio(1);
    #pragma unroll
    for (int mf = 0; mf < 4; ++mf)
      #pragma unroll
      for (int nf = 0; nf < 2; ++nf) {
        acc[mf][2 + nf] = __builtin_amdgcn_mfma_f32_16x16x32_bf16(af[mf][0], bf2[nf][0], acc[mf][2 + nf], 0, 0, 0);
        acc[mf][2 + nf] = __builtin_amdgcn_mfma_f32_16x16x32_bf16(af[mf][1], bf2[nf][1], acc[mf][2 + nf], 0, 0, 0);
      }
    __builtin_amdgcn_s_setprio(0);
    S_BARRIER();

    // ---- phase 2
    #pragma unroll
    for (int mf = 0; mf < 4; ++mf) {
      af[mf][0] = *(const short8*)(Al + arow0 + (4 + mf) * 1024 + g0);
      af[mf][1] = *(const short8*)(Al + arow0 + (4 + mf) * 1024 + g1);
    }
    stageB(kt2, 0); stageB(kt2, 1);
    S_BARRIER();
    __builtin_amdgcn_s_setprio(1);
    #pragma unroll
    for (int mf = 0; mf < 4; ++mf)
      #pragma unroll
      for (int nf = 0; nf < 2; ++nf) {
        acc[4 + mf][nf] = __builtin_amdgcn_mfma_f32_16x16x32_bf16(af[mf][0], bf[nf][0], acc[4 + mf][nf], 0, 0, 0);
        acc[4 + mf][nf] = __builtin_amdgcn_mfma_f32_16x16x32_bf16(af[mf][1], bf[nf][1], acc[4 + mf][nf], 0, 0, 0);
      }
    __builtin_amdgcn_s_setprio(0);
    S_BARRIER();

    // ---- phase 3
    stageB(kt2, 2); stageB(kt2, 3);
    WAIT_VM(4);
    S_BARRIER();
    __builtin_amdgcn_s_setprio(1);
    #pragma unroll
    for (int mf = 0; mf < 4; ++mf)
      #pragma unroll
      for (int nf = 0; nf < 2; ++nf) {
        acc[4 + mf][2 + nf] = __builtin_amdgcn_mfma_f32_16x16x32_bf16(af[mf][0], bf2[nf][0], acc[4 + mf][2 + nf], 0, 0, 0);
        acc[4 + mf][2 + nf] = __builtin_amdgcn_mfma_f32_16x16x32_bf16(af[mf][1], bf2[nf][1], acc[4 + mf][2 + nf], 0, 0, 0);
      }
    __builtin_amdgcn_s_setprio(0);
    S_BARRIER();
  }

  WAIT_VM(0);   // drain wrapped DMA stages before LDS reuse / exit

  if (OUT_BF16) {
    unsigned short* Ost = lds + wave * 4096;
    const int cb = bn * 256 + wn * 64;
    #pragma unroll
    for (int p = 0; p < 2; ++p) {
      #pragma unroll
      for (int nf = 0; nf < 4; ++nf) {
        const float bv = bias[cb + nf * 16 + lr];
        #pragma unroll
        for (int mh = 0; mh < 4; ++mh)
          #pragma unroll
          for (int r = 0; r < 4; ++r) {
            const int row = mh * 16 + lq * 4 + r;
            Ost[row * 64 + ((nf * 16 + lr) ^ (lq << 4))] =
                f2bf_bits(acc[p * 4 + mh][nf][r] + bv);
          }
      }
      #pragma unroll
      for (int k = 0; k < 8; ++k) {
        const int cid = k * 64 + lane;
        const int row = cid >> 3;          // 0..63
        const int c8  = cid & 7;
        const int lqr = (row >> 2) & 3;
        short8 v = *(const short8*)(Ost + row * 64 + ((c8 * 8) ^ (lqr << 4)));
        const size_t grow = (size_t)(bm * 256 + wm * 128 + p * 64 + row);
        *(short8*)((unsigned short*)Cout + grow * N + cb + c8 * 8) = v;
      }
    }
  } else {
    const int rbase = bm * 256 + wm * 128 + lq * 4;
    const int cbase = bn * 256 + wn * 64 + lr;
    #pragma unroll
    for (int nf = 0; nf < 4; ++nf) {
      const int col = cbase + nf * 16;
      const float bv = bias[col];
      #pragma unroll
      for (int mf = 0; mf < 8; ++mf) {
        const int row = rbase + mf * 16;
        #pragma unroll
        for (int r = 0; r < 4; ++r)
          ((float*)Cout)[(size_t)(row + r) * N + col] = acc[mf][nf][r] + bv;
      }
    }
  }
}

// ---------------- window attention: register-direct, 1 lgkm barrier/window -
// Q and K load straight into MFMA fragment registers from global (no LDS, no
// DMA). V is cooperatively transposed through Vt[dbuf] (the only cross-wave
// LDS) -> barrier per window needs only lgkmcnt(0). P/O go through a
// wave-private 16x64 strip. All loads for window i+1 issue during window i
// and are never drained by the barrier.
#define WPB 4

__global__ __launch_bounds__(256, 4) void win_attn(
    const unsigned short* __restrict__ qkv,  // [32768, 3072] bf16
    unsigned short* __restrict__ out)        // [32768, 1024] bf16
{
  __shared__ unsigned short Vt[2][64 * 64];  // V^T, swizzled, 8 KB each
  __shared__ unsigned short Ps[4 * 16 * 64]; // per-wave private strips, 8 KB

  const int t    = threadIdx.x;
  const int wave = t >> 6;
  const int lane = t & 63;
  const int lr   = lane & 15;
  const int lq   = lane >> 4;
  const int k7   = lane & 7;
  const int kh   = lane >> 3;
  const int gbase = blockIdx.x * WPB;
  unsigned short* Pst = Ps + wave * 1024;

  short8 qa[2], kf[4][2], vr[2];

  auto qptr = [&](int g) {
    const int b = g >> 11, h = (g >> 7) & 15, wi = g & 127;
    return qkv + (size_t)(b * 8192 + wi * 64) * 3072 + h * 64;
  };
  auto loadV = [&](const unsigned short* vb) {
    #pragma unroll
    for (int o = 0; o < 2; ++o)
      vr[o] = *(const short8*)(vb + (size_t)lane * 3072 + wave * 8 + o * 32);
  };
  auto loadQ = [&](const unsigned short* qb) {
    #pragma unroll
    for (int k2 = 0; k2 < 2; ++k2)
      qa[k2] = *(const short8*)(qb + (size_t)(wave * 16 + lr) * 3072 + k2 * 32 + lq * 8);
  };
  auto loadK = [&](const unsigned short* kb) {
    // B-frag direct: lane (lr,lq) holds K[key=jt*16+lr][k2*32+lq*8 .. +8)
    #pragma unroll
    for (int jt = 0; jt < 4; ++jt)
      #pragma unroll
      for (int k2 = 0; k2 < 2; ++k2)
        kf[jt][k2] = *(const short8*)(kb + (size_t)(jt * 16 + lr) * 3072 + k2 * 32 + lq * 8);
  };
  auto scatterV = [&](int s) {
    // vr[o][j] = V[key=lane][d+j], d = wave*8+o*32; 16B-unit col ^ (d&7)
    #pragma unroll
    for (int o = 0; o < 2; ++o) {
      const int d = wave * 8 + o * 32;
      #pragma unroll
      for (int j = 0; j < 8; ++j)
        Vt[s][(d + j) * 64 + k7 + ((kh ^ j) << 3)] = vr[o][j];
    }
  };

  // prologue: window 0 (V, K, Q issued; scatter waits only the V loads)
  {
    const unsigned short* qb0 = qptr(gbase);
    loadV(qb0 + 2048);
    loadK(qb0 + 1024);
    loadQ(qb0);
    scatterV(0);
    WAIT_LGKM0();
    S_BARRIER();
  }

  for (int i = 0; i < WPB; ++i) {
    const int c = i & 1;
    const int g = gbase + i;
    const int h = (g >> 7) & 15;
    const int tok0 = ((g >> 11) * 8192) + (g & 127) * 64;
    const bool more = (i + 1 < WPB);
    const unsigned short* qb1 = qptr(more ? g + 1 : g);

    if (more) loadV(qb1 + 2048);

    // S = Q K^T  (both operands in registers)
    float4v s4[4];
    #pragma unroll
    for (int jt = 0; jt < 4; ++jt) {
      float4v a = (float4v){0.f, 0.f, 0.f, 0.f};
      #pragma unroll
      for (int k2 = 0; k2 < 2; ++k2)
        a = __builtin_amdgcn_mfma_f32_16x16x32_bf16(qa[k2], kf[jt][k2], a, 0, 0, 0);
      s4[jt] = a;
    }

    if (more) { loadK(qb1 + 1024); loadQ(qb1); }  // frags dead after QK

    // softmax (q-row = wave*16+lq*4+r; keys over jt x lr 16-lane groups)
    const float scale = 0.125f;  // 1/sqrt(64)
    float pr[4][4];
    #pragma unroll
    for (int r = 0; r < 4; ++r) {
      float m = s4[0][r];
      #pragma unroll
      for (int jt = 1; jt < 4; ++jt) m = fmaxf(m, s4[jt][r]);
      #pragma unroll
      for (int off = 1; off < 16; off <<= 1) m = fmaxf(m, __shfl_xor(m, off));
      float sum = 0.f;
      #pragma unroll
      for (int jt = 0; jt < 4; ++jt) {
        float e = __expf((s4[jt][r] - m) * scale);
        pr[jt][r] = e; sum += e;
      }
      #pragma unroll
      for (int off = 1; off < 16; off <<= 1) sum += __shfl_xor(sum, off);
      float inv = 1.0f / sum;
      #pragma unroll
      for (int jt = 0; jt < 4; ++jt) pr[jt][r] *= inv;
    }

    // P -> wave-private strip (16B-unit swizzle c8' = c8 ^ (row&7))
    #pragma unroll
    for (int jt = 0; jt < 4; ++jt)
      #pragma unroll
      for (int r = 0; r < 4; ++r) {
        const int row = lq * 4 + r;
        const int cu  = (jt * 2 + (lr >> 3)) ^ (row & 7);
        Pst[row * 64 + (cu << 3) + (lr & 7)] = f2bf_bits(pr[jt][r]);
      }
    short8 pa[2];
    #pragma unroll
    for (int k2 = 0; k2 < 2; ++k2)
      pa[k2] = *(const short8*)(&Pst[lr * 64 + (((k2 * 4 + lq) ^ (lr & 7)) << 3)]);

    // O = P V
    float4v o4[4];
    #pragma unroll
    for (int jd = 0; jd < 4; ++jd) {
      float4v a = (float4v){0.f, 0.f, 0.f, 0.f};
      #pragma unroll
      for (int k2 = 0; k2 < 2; ++k2) {
        short8 vf = *(const short8*)(&Vt[c][(jd * 16 + lr) * 64 +
                                            (((k2 * 4 + lq) ^ (lr & 7)) << 3)]);
        a = __builtin_amdgcn_mfma_f32_16x16x32_bf16(pa[k2], vf, a, 0, 0, 0);
      }
      o4[jd] = a;
    }

    if (more) scatterV(c ^ 1);  // waits only the vr loads (counted)

    // O out via wave-private strip repack, short8 stores
    #pragma unroll
    for (int jd = 0; jd < 4; ++jd)
      #pragma unroll
      for (int r = 0; r < 4; ++r)
        Pst[(lq * 4 + r) * 64 + ((jd * 16 + lr) ^ (lq << 4))] = f2bf_bits(o4[jd][r]);
    #pragma unroll
    for (int k = 0; k < 2; ++k) {
      const int cid = k * 64 + lane;
      const int row = cid >> 3;          // 0..15
      const int c8  = cid & 7;
      const int lqr = (row >> 2) & 3;
      short8 v = *(const short8*)(&Pst[row * 64 + ((c8 * 8) ^ (lqr << 4))]);
      *(short8*)(out + (size_t)(tok0 + wave * 16 + row) * 1024 + h * 64 + c8 * 8) = v;
    }

    if (more) {
      WAIT_LGKM0();   // Vt[c^1] scatter visible to other waves
      S_BARRIER();    // no vmem drain: prefetch + O stores stay in flight
    }
  }
}

// ---------------- launch ---------------------------------------------------
extern "C" void kernel_launch(void* const* d_in, const int* in_sizes, int n_in,
                              void* d_out, int out_size, void* d_ws, size_t ws_size,
                              hipStream_t stream) {
  const float* x      = (const float*)d_in[0];  // [4,8192,1024]
  const float* w_qkv  = (const float*)d_in[1];  // [3072,1024]
  const float* b_qkv  = (const float*)d_in[2];  // [3072]
  const float* w_proj = (const float*)d_in[3];  // [1024,1024]
  const float* b_proj = (const float*)d_in[4];  // [1024]
  float* outp = (float*)d_out;                  // [4,8192,1024] fp32

  char* ws = (char*)d_ws;
  unsigned short* xb     = (unsigned short*)(ws);
  unsigned short* wqkvb  = (unsigned short*)(ws + 67108864);
  unsigned short* wprojb = (unsigned short*)(ws + 73400320);
  unsigned short* qkvb   = (unsigned short*)(ws + 75497472);
  unsigned short* attnb  = (unsigned short*)(ws + 276824064);

  static int attr_done = 0;
  if (!attr_done) {
    hipFuncSetAttribute(reinterpret_cast<const void*>(&gemm256<true>),
                        hipFuncAttributeMaxDynamicSharedMemorySize, 131072);
    hipFuncSetAttribute(reinterpret_cast<const void*>(&gemm256<false>),
                        hipFuncAttributeMaxDynamicSharedMemorySize, 131072);
    attr_done = 1;
  }

  cast_f32_to_bf16<<<32768, 256, 0, stream>>>(x,      xb,     33554432 / 4);
  cast_f32_to_bf16<<<3072,  256, 0, stream>>>(w_qkv,  wqkvb,  3145728 / 4);
  cast_f32_to_bf16<<<1024,  256, 0, stream>>>(w_proj, wprojb, 1048576 / 4);

  // qkv = x @ w_qkv^T + b_qkv : M=32768, N=3072, K=1024 (mtiles=128, ntiles=12)
  gemm256<true><<<128 * 12, 512, 131072, stream>>>(xb, wqkvb, b_qkv, qkvb,
                                                   32768, 3072, 1024, 12);
  // block-diagonal window attention: 8192 windows, 4 per block
  win_attn<<<8192 / WPB, 256, 0, stream>>>(qkvb, attnb);
  // out = attn @ w_proj^T + b_proj : M=32768, N=1024, K=1024 (ntiles=4)
  gemm256<false><<<128 * 4, 512, 131072, stream>>>(attnb, wprojb, b_proj, outp,
                                                   32768, 1024, 1024, 4);
}

// Round 7
// 579.924 us; speedup vs baseline: 1.0172x; 1.0172x over previous
//
#include <hip/hip_runtime.h>
#include <hip/hip_bf16.h>
#include <cstdint>
#include <cstddef>

// HierarchicalAttention on MI355X (gfx950).
// R10 change: win_attn = R9's one-wave-one-window structure (no barriers, no
// cross-wave LDS, no DMA) with the V path rebuilt on HW-proven patterns.
// R9's 256 fully-unrolled scalar global gathers for V (the only truly novel
// construct) is the prime suspect for the container failure; replaced by:
//   V -> 8x short8 row loads (R8's passing pattern) -> transposed+swizzled
//   ds_write_b16 scatter (R8's 2-way-bank formula) -> 8x ds_read_b128 into
//   vf[4][2] regs (gemm256's measured-0-conflict read shape).
// Wave-private 64x64 strip lifecycle: P -> pa(regs) -> V^T -> vf(regs) -> O.
// Register peak ~106 < 128 cap of launch_bounds(256,4); LDS 32KB -> 4
// blocks/CU, 16 fully independent waves.
// gemm256 (208us qkv = 991 TF, FETCH/WRITE at ideal, 0 conflicts) unchanged.
//
// Workspace layout (total 343,932,928 B):
//   [0)            x_bf16     [32768,1024]  67,108,864 B
//   [67108864)     wqkv_bf16  [3072,1024]    6,291,456 B
//   [73400320)     wproj_bf16 [1024,1024]    2,097,152 B
//   [75497472)     qkv_bf16   [32768,3072] 201,326,592 B
//   [276824064)    attn_bf16  [32768,1024]  67,108,864 B

typedef __attribute__((ext_vector_type(8))) short short8;
typedef __attribute__((ext_vector_type(4))) float float4v;

static __device__ __forceinline__ void async16(void* lds_p, const void* g) {
  __builtin_amdgcn_global_load_lds((const __attribute__((address_space(1))) void*)g,
                                   (__attribute__((address_space(3))) void*)lds_p,
                                   16, 0, 0);
}

static __device__ __forceinline__ unsigned short f2bf_bits(float x) {
  unsigned int u = __float_as_uint(x);
  unsigned int r = (u + 0x7fffu + ((u >> 16) & 1u)) >> 16;  // RNE
  return (unsigned short)r;
}

#define S_BARRIER() asm volatile("s_barrier" ::: "memory")
#define WAIT_VM(n)  asm volatile("s_waitcnt vmcnt(" #n ")" ::: "memory")

// ---------------- cast fp32 -> bf16 (vectorized) ---------------------------
__global__ __launch_bounds__(256) void cast_f32_to_bf16(
    const float* __restrict__ in, unsigned short* __restrict__ out, int n4) {
  int i = blockIdx.x * 256 + threadIdx.x;
  if (i >= n4) return;
  float4 v = ((const float4*)in)[i];
  ushort4 o;
  o.x = f2bf_bits(v.x); o.y = f2bf_bits(v.y);
  o.z = f2bf_bits(v.z); o.w = f2bf_bits(v.w);
  ((ushort4*)out)[i] = o;
}

// ---------------- GEMM: C[M,N] = A[M,K] * B[N,K]^T + bias ------------------
// 256x256 tile, BK=64, 8 waves (2Mx4N), 8-phase counted-vmcnt schedule
// (T1..T5) + bf16 LDS-repack epilogue. Unchanged from R4.
template<bool OUT_BF16>
__global__ __launch_bounds__(512, 2) void gemm256(
    const unsigned short* __restrict__ A,   // [M,K] bf16 bits
    const unsigned short* __restrict__ B,   // [N,K] bf16 bits
    const float* __restrict__ bias,         // [N]
    void* __restrict__ Cout,                // [M,N] bf16 or fp32
    int M, int N, int K, int ntiles)
{
  extern __shared__ unsigned short lds[];

  const int t    = threadIdx.x;             // 0..511
  const int wave = t >> 6;
  const int lane = t & 63;
  const int lr   = lane & 15;
  const int lq   = lane >> 4;
  const int wm   = wave >> 2;               // 0..1
  const int wn   = wave & 3;                // 0..3

  const int nwg  = gridDim.x;
  const int q8   = nwg >> 3;
  const int wg   = ((int)blockIdx.x & 7) * q8 + ((int)blockIdx.x >> 3);
  const int GM   = 8;
  const int group = wg / (GM * ntiles);
  const int inG   = wg % (GM * ntiles);
  const int bm    = group * GM + (inG % GM);
  const int bn    = inG / GM;

  const int srow = t >> 3;                            // 0..63 within chunk
  const int sswz = ((t & 7) ^ (srow & 7)) << 3;       // swizzled col (elems)
  const unsigned short* Abase = A + (size_t)(bm * 256 + srow) * K + sswz;
  const unsigned short* Bbase = B + (size_t)(bn * 256 + srow) * K + sswz;
  const int ldsw = wave * 512;

  auto stageA = [&](int kt, int c) {
    async16(lds + (kt & 1) * 16384 + c * 4096 + ldsw,
            Abase + (size_t)(c * 64) * K + kt * 64);
  };
  auto stageB = [&](int kt, int c) {
    async16(lds + 32768 + (kt & 1) * 16384 + c * 4096 + ldsw,
            Bbase + (size_t)(c * 64) * K + kt * 64);
  };

  const int g0 = ((0 + lq) ^ (lr & 7)) << 3;
  const int g1 = ((4 + lq) ^ (lr & 7)) << 3;
  const int arow0 = (wm * 128 + lr) * 64;
  const int brow0 = (wn * 64 + lr) * 64;

  float4v acc[8][4];
  #pragma unroll
  for (int i = 0; i < 8; ++i)
    #pragma unroll
    for (int j = 0; j < 4; ++j) acc[i][j] = (float4v){0.f, 0.f, 0.f, 0.f};

  const int NT = K >> 6;

  #pragma unroll
  for (int c = 0; c < 4; ++c) stageB(0, c);
  #pragma unroll
  for (int c = 0; c < 4; ++c) stageA(0, c);
  #pragma unroll
  for (int c = 0; c < 4; ++c) stageB(1, c);
  WAIT_VM(4);
  S_BARRIER();

  short8 af[4][2], bf[2][2], bf2[2][2];

  for (int kt = 0; kt < NT; ++kt) {
    const int bc = kt & 1;
    int kt1 = kt + 1; if (kt1 == NT) kt1 = 0;
    int kt2 = kt + 2; if (kt2 >= NT) kt2 -= NT;
    const unsigned short* Al = lds + bc * 16384;
    const unsigned short* Bl = lds + 32768 + bc * 16384;

    // ---- phase 0
    #pragma unroll
    for (int mf = 0; mf < 4; ++mf) {
      af[mf][0] = *(const short8*)(Al + arow0 + mf * 1024 + g0);
      af[mf][1] = *(const short8*)(Al + arow0 + mf * 1024 + g1);
    }
    #pragma unroll
    for (int nf = 0; nf < 2; ++nf) {
      bf[nf][0] = *(const short8*)(Bl + brow0 + nf * 1024 + g0);
      bf[nf][1] = *(const short8*)(Bl + brow0 + nf * 1024 + g1);
    }
    stageA(kt1, 0); stageA(kt1, 2);
    S_BARRIER();
    __builtin_amdgcn_s_setprio(1);
    #pragma unroll
    for (int mf = 0; mf < 4; ++mf)
      #pragma unroll
      for (int nf = 0; nf < 2; ++nf) {
        acc[mf][nf] = __builtin_amdgcn_mfma_f32_16x16x32_bf16(af[mf][0], bf[nf][0], acc[mf][nf], 0, 0, 0);
        acc[mf][nf] = __builtin_amdgcn_mfma_f32_16x16x32_bf16(af[mf][1], bf[nf][1], acc[mf][nf], 0, 0, 0);
      }
    __builtin_amdgcn_s_setprio(0);
    S_BARRIER();

    // ---- phase 1
    #pragma unroll
    for (int nf = 0; nf < 2; ++nf) {
      bf2[nf][0] = *(const short8*)(Bl + brow0 + (2 + nf) * 1024 + g0);
      bf2[nf][1] = *(const short8*)(Bl + brow0 + (2 + nf) * 1024 + g1);
    }
    stageA(kt1, 1); stageA(kt1, 3);
    S_BARRIER();
    __builtin_amdgcn_s_setprio(1);
    #pragma unroll
    for (int mf = 0; mf < 4; ++mf)
      #pragma unroll
      for (int nf = 0; nf < 2; ++nf) {
        acc[mf][2 + nf] = __builtin_amdgcn_mfma_f32_16x16x32_bf16(af[mf][0], bf2[nf][0], acc[mf][2 + nf], 0, 0, 0);
        acc[mf][2 + nf] = __builtin_amdgcn_mfma_f32_16x16x32_bf16(af[mf][1], bf2[nf][1], acc[mf][2 + nf], 0, 0, 0);
      }
    __builtin_amdgcn_s_setprio(0);
    S_BARRIER();

    // ---- phase 2
    #pragma unroll
    for (int mf = 0; mf < 4; ++mf) {
      af[mf][0] = *(const short8*)(Al + arow0 + (4 + mf) * 1024 + g0);
      af[mf][1] = *(const short8*)(Al + arow0 + (4 + mf) * 1024 + g1);
    }
    stageB(kt2, 0); stageB(kt2, 1);
    S_BARRIER();
    __builtin_amdgcn_s_setprio(1);
    #pragma unroll
    for (int mf = 0; mf < 4; ++mf)
      #pragma unroll
      for (int nf = 0; nf < 2; ++nf) {
        acc[4 + mf][nf] = __builtin_amdgcn_mfma_f32_16x16x32_bf16(af[mf][0], bf[nf][0], acc[4 + mf][nf], 0, 0, 0);
        acc[4 + mf][nf] = __builtin_amdgcn_mfma_f32_16x16x32_bf16(af[mf][1], bf[nf][1], acc[4 + mf][nf], 0, 0, 0);
      }
    __builtin_amdgcn_s_setprio(0);
    S_BARRIER();

    // ---- phase 3
    stageB(kt2, 2); stageB(kt2, 3);
    WAIT_VM(4);
    S_BARRIER();
    __builtin_amdgcn_s_setprio(1);
    #pragma unroll
    for (int mf = 0; mf < 4; ++mf)
      #pragma unroll
      for (int nf = 0; nf < 2; ++nf) {
        acc[4 + mf][2 + nf] = __builtin_amdgcn_mfma_f32_16x16x32_bf16(af[mf][0], bf2[nf][0], acc[4 + mf][2 + nf], 0, 0, 0);
        acc[4 + mf][2 + nf] = __builtin_amdgcn_mfma_f32_16x16x32_bf16(af[mf][1], bf2[nf][1], acc[4 + mf][2 + nf], 0, 0, 0);
      }
    __builtin_amdgcn_s_setprio(0);
    S_BARRIER();
  }

  WAIT_VM(0);   // drain wrapped DMA stages before LDS reuse / exit

  if (OUT_BF16) {
    unsigned short* Ost = lds + wave * 4096;
    const int cb = bn * 256 + wn * 64;
    #pragma unroll
    for (int p = 0; p < 2; ++p) {
      #pragma unroll
      for (int nf = 0; nf < 4; ++nf) {
        const float bv = bias[cb + nf * 16 + lr];
        #pragma unroll
        for (int mh = 0; mh < 4; ++mh)
          #pragma unroll
          for (int r = 0; r < 4; ++r) {
            const int row = mh * 16 + lq * 4 + r;
            Ost[row * 64 + ((nf * 16 + lr) ^ (lq << 4))] =
                f2bf_bits(acc[p * 4 + mh][nf][r] + bv);
          }
      }
      #pragma unroll
      for (int k = 0; k < 8; ++k) {
        const int cid = k * 64 + lane;
        const int row = cid >> 3;          // 0..63
        const int c8  = cid & 7;
        const int lqr = (row >> 2) & 3;
        short8 v = *(const short8*)(Ost + row * 64 + ((c8 * 8) ^ (lqr << 4)));
        const size_t grow = (size_t)(bm * 256 + wm * 128 + p * 64 + row);
        *(short8*)((unsigned short*)Cout + grow * N + cb + c8 * 8) = v;
      }
    }
  } else {
    const int rbase = bm * 256 + wm * 128 + lq * 4;
    const int cbase = bn * 256 + wn * 64 + lr;
    #pragma unroll
    for (int nf = 0; nf < 4; ++nf) {
      const int col = cbase + nf * 16;
      const float bv = bias[col];
      #pragma unroll
      for (int mf = 0; mf < 8; ++mf) {
        const int row = rbase + mf * 16;
        #pragma unroll
        for (int r = 0; r < 4; ++r)
          ((float*)Cout)[(size_t)(row + r) * N + col] = acc[mf][nf][r] + bv;
      }
    }
  }
}

// ---------------- window attention: one wave = one window ------------------
// Zero barriers, zero cross-wave traffic. Strip lifecycle per wave:
//   P (swizzled)  -> pa regs
//   V^T (swizzled)-> vf regs
//   O (swizzled)  -> coalesced short8 stores
__global__ __launch_bounds__(256, 4) void win_attn(
    const unsigned short* __restrict__ qkv,  // [32768, 3072] bf16
    unsigned short* __restrict__ out)        // [32768, 1024] bf16
{
  __shared__ unsigned short Ps[4][64 * 64];  // wave-private strips, 32 KB

  const int t    = threadIdx.x;
  const int wave = t >> 6;
  const int lane = t & 63;
  const int lr   = lane & 15;
  const int lq   = lane >> 4;
  const int kh   = lane >> 3;                // 0..7
  const int k7   = lane & 7;

  const int g    = blockIdx.x * 4 + wave;    // 0..8191
  const int h    = (g >> 7) & 15;
  const int tok0 = ((g >> 11) * 8192) + (g & 127) * 64;
  const unsigned short* qb = qkv + (size_t)tok0 * 3072 + h * 64;
  const unsigned short* kb = qb + 1024;
  const unsigned short* vb = qb + 2048;
  unsigned short* Pst = Ps[wave];

  // K B-frags + V rows: all global loads issued up front (latency overlaps S)
  short8 kf[4][2];
  #pragma unroll
  for (int jt = 0; jt < 4; ++jt)
    #pragma unroll
    for (int k2 = 0; k2 < 2; ++k2)
      kf[jt][k2] = *(const short8*)(kb + (size_t)(jt * 16 + lr) * 3072 + k2 * 32 + lq * 8);

  short8 vrow[8];   // vrow[o] = V[key=lane][d = o*8 .. +8)  (R8's passing pattern)
  #pragma unroll
  for (int o = 0; o < 8; ++o)
    vrow[o] = *(const short8*)(vb + (size_t)lane * 3072 + o * 8);

  const float scale = 0.125f;  // 1/sqrt(64)

  // S + softmax + P-store per 16-row m-tile (keeps regs low)
  #pragma unroll
  for (int mt = 0; mt < 4; ++mt) {
    short8 qa[2];
    #pragma unroll
    for (int k2 = 0; k2 < 2; ++k2)
      qa[k2] = *(const short8*)(qb + (size_t)(mt * 16 + lr) * 3072 + k2 * 32 + lq * 8);

    float4v s4[4];
    #pragma unroll
    for (int jt = 0; jt < 4; ++jt) {
      float4v a = (float4v){0.f, 0.f, 0.f, 0.f};
      #pragma unroll
      for (int k2 = 0; k2 < 2; ++k2)
        a = __builtin_amdgcn_mfma_f32_16x16x32_bf16(qa[k2], kf[jt][k2], a, 0, 0, 0);
      s4[jt] = a;  // S[q=mt*16+lq*4+r][key=jt*16+lr]
    }

    #pragma unroll
    for (int r = 0; r < 4; ++r) {
      float m = s4[0][r];
      #pragma unroll
      for (int jt = 1; jt < 4; ++jt) m = fmaxf(m, s4[jt][r]);
      #pragma unroll
      for (int off = 1; off < 16; off <<= 1) m = fmaxf(m, __shfl_xor(m, off));
      float sum = 0.f;
      float pr[4];
      #pragma unroll
      for (int jt = 0; jt < 4; ++jt) {
        float e = __expf((s4[jt][r] - m) * scale);
        pr[jt] = e; sum += e;
      }
      #pragma unroll
      for (int off = 1; off < 16; off <<= 1) sum += __shfl_xor(sum, off);
      float inv = 1.0f / sum;
      // P -> strip: unit (key>>3)^(row&7), offset key&7, key = jt*16+lr
      const int row = mt * 16 + lq * 4 + r;
      #pragma unroll
      for (int jt = 0; jt < 4; ++jt) {
        const int cu = (jt * 2 + (lr >> 3)) ^ (row & 7);
        Pst[row * 64 + (cu << 3) + (lr & 7)] = f2bf_bits(pr[jt] * inv);
      }
    }
  }

  // pa <- strip: pa[mt][k2][j] = P[q=mt*16+lr][key=k2*32+lq*8+j]
  short8 pa[4][2];
  #pragma unroll
  for (int mt = 0; mt < 4; ++mt)
    #pragma unroll
    for (int k2 = 0; k2 < 2; ++k2)
      pa[mt][k2] = *(const short8*)(&Pst[(mt * 16 + lr) * 64 +
                                         (((k2 * 4 + lq) ^ (lr & 7)) << 3)]);

  // V^T -> strip (strip free after pa): Vt[d][key] at
  //   d*64 + (((key>>3) ^ (d&7)) << 3) + (key&7);  key = lane, d = o*8+j.
  // Write banks: ((kh^j)*4 + (k7>>1)) & 31 -> 32 banks, 2 lanes each (free).
  #pragma unroll
  for (int o = 0; o < 8; ++o)
    #pragma unroll
    for (int j = 0; j < 8; ++j)
      Pst[(o * 8 + j) * 64 + ((kh ^ j) << 3) + k7] = vrow[o][j];

  // vf <- strip (V^T then dead): vf[jd][k2][j] = V[k=k2*32+lq*8+j][d=jd*16+lr]
  short8 vf[4][2];
  #pragma unroll
  for (int jd = 0; jd < 4; ++jd)
    #pragma unroll
    for (int k2 = 0; k2 < 2; ++k2)
      vf[jd][k2] = *(const short8*)(&Pst[(jd * 16 + lr) * 64 +
                                         (((k2 * 4 + lq) ^ (lr & 7)) << 3)]);

  // O = P V per m-tile -> strip (strip dead), col swizzle ^ (lq<<4)
  #pragma unroll
  for (int mt = 0; mt < 4; ++mt)
    #pragma unroll
    for (int jd = 0; jd < 4; ++jd) {
      float4v a = (float4v){0.f, 0.f, 0.f, 0.f};
      #pragma unroll
      for (int k2 = 0; k2 < 2; ++k2)
        a = __builtin_amdgcn_mfma_f32_16x16x32_bf16(pa[mt][k2], vf[jd][k2], a, 0, 0, 0);
      #pragma unroll
      for (int r = 0; r < 4; ++r) {
        const int row = mt * 16 + lq * 4 + r;
        Pst[row * 64 + ((jd * 16 + lr) ^ (lq << 4))] = f2bf_bits(a[r]);
      }
    }

  // strip -> global, 16B coalesced (read swizzle mirrors write: lq == (row>>2)&3)
  #pragma unroll
  for (int k = 0; k < 8; ++k) {
    const int cid = k * 64 + lane;
    const int row = cid >> 3;          // 0..63
    const int c8  = cid & 7;
    const int lqr = (row >> 2) & 3;
    short8 v = *(const short8*)(&Pst[row * 64 + ((c8 * 8) ^ (lqr << 4))]);
    *(short8*)(out + (size_t)(tok0 + row) * 1024 + h * 64 + c8 * 8) = v;
  }
}

// ---------------- launch ---------------------------------------------------
extern "C" void kernel_launch(void* const* d_in, const int* in_sizes, int n_in,
                              void* d_out, int out_size, void* d_ws, size_t ws_size,
                              hipStream_t stream) {
  const float* x      = (const float*)d_in[0];  // [4,8192,1024]
  const float* w_qkv  = (const float*)d_in[1];  // [3072,1024]
  const float* b_qkv  = (const float*)d_in[2];  // [3072]
  const float* w_proj = (const float*)d_in[3];  // [1024,1024]
  const float* b_proj = (const float*)d_in[4];  // [1024]
  float* outp = (float*)d_out;                  // [4,8192,1024] fp32

  char* ws = (char*)d_ws;
  unsigned short* xb     = (unsigned short*)(ws);
  unsigned short* wqkvb  = (unsigned short*)(ws + 67108864);
  unsigned short* wprojb = (unsigned short*)(ws + 73400320);
  unsigned short* qkvb   = (unsigned short*)(ws + 75497472);
  unsigned short* attnb  = (unsigned short*)(ws + 276824064);

  static int attr_done = 0;
  if (!attr_done) {
    hipFuncSetAttribute(reinterpret_cast<const void*>(&gemm256<true>),
                        hipFuncAttributeMaxDynamicSharedMemorySize, 131072);
    hipFuncSetAttribute(reinterpret_cast<const void*>(&gemm256<false>),
                        hipFuncAttributeMaxDynamicSharedMemorySize, 131072);
    attr_done = 1;
  }

  cast_f32_to_bf16<<<32768, 256, 0, stream>>>(x,      xb,     33554432 / 4);
  cast_f32_to_bf16<<<3072,  256, 0, stream>>>(w_qkv,  wqkvb,  3145728 / 4);
  cast_f32_to_bf16<<<1024,  256, 0, stream>>>(w_proj, wprojb, 1048576 / 4);

  // qkv = x @ w_qkv^T + b_qkv : M=32768, N=3072, K=1024 (mtiles=128, ntiles=12)
  gemm256<true><<<128 * 12, 512, 131072, stream>>>(xb, wqkvb, b_qkv, qkvb,
                                                   32768, 3072, 1024, 12);
  // block-diagonal window attention: 8192 windows, one per wave, 4 per block
  win_attn<<<8192 / 4, 256, 0, stream>>>(qkvb, attnb);
  // out = attn @ w_proj^T + b_proj : M=32768, N=1024, K=1024 (ntiles=4)
  gemm256<false><<<128 * 4, 512, 131072, stream>>>(attnb, wprojb, b_proj, outp,
                                                   32768, 1024, 1024, 4);
}